// Round 9
// baseline (140.718 us; speedup 1.0000x reference)
//
#include <hip/hip_runtime.h>

typedef unsigned short u16;
typedef float f32x4 __attribute__((ext_vector_type(4)));
typedef unsigned int u32x4 __attribute__((ext_vector_type(4)));
typedef unsigned short u16x4 __attribute__((ext_vector_type(4)));
typedef unsigned short u16x8 __attribute__((ext_vector_type(8)));
typedef __bf16 bf16x8 __attribute__((ext_vector_type(8)));

#define DEVFN static __device__ __forceinline__

DEVFN float bf2f(u16 u) {
    unsigned int i = ((unsigned int)u) << 16;
    float f;
    __builtin_memcpy(&f, &i, 4);
    return f;
}
DEVFN u16 f2bf(float f) {
    unsigned int i;
    __builtin_memcpy(&i, &f, 4);
    unsigned int r = i + 0x7fffu + ((i >> 16) & 1u);
    return (u16)(r >> 16);
}

DEVFN bf16x8 ldb(const u16* p) { return __builtin_bit_cast(bf16x8, *(const u16x8*)p); }

// 16x16x32: C/D: col=lane&15 (Brow), row=(lane>>4)*4+reg (Arow)  (HW-verified r2)
DEVFN f32x4 mfma16(bf16x8 a, bf16x8 b, f32x4 c) {
    return __builtin_amdgcn_mfma_f32_16x16x32_bf16(a, b, c, 0, 0, 0);
}

// ---------------- weight convert: fp32 -> bf16 ----------------
__global__ __launch_bounds__(256) void k_cvtw(const float* __restrict__ pt,
                                              const float* __restrict__ q,
                                              const float* __restrict__ k,
                                              const float* __restrict__ v,
                                              const float* __restrict__ o,
                                              const float* __restrict__ f,
                                              u16* __restrict__ dst) {
    int i = blockIdx.x * 256 + threadIdx.x;  // grid covers exactly 147456
    const float* s;
    int off;
    if (i < 65536)       { s = pt; off = i; }
    else if (i < 81920)  { s = q;  off = i - 65536; }
    else if (i < 98304)  { s = k;  off = i - 81920; }
    else if (i < 114688) { s = v;  off = i - 98304; }
    else if (i < 131072) { s = o;  off = i - 114688; }
    else                 { s = f;  off = i - 131072; }
    dst[i] = f2bf(s[off]);
}

// ---------------- per-batch mask sum + Q scale ----------------
__global__ __launch_bounds__(256) void k_nsum(const int* __restrict__ mask,
                                              int* __restrict__ nsumI,
                                              float* __restrict__ scaleQ) {
    __shared__ int sred[4];
    int tid = threadIdx.x, b = blockIdx.x;
    int4 mm = *(const int4*)&mask[(b << 10) + tid * 4];
    int part = mm.x + mm.y + mm.z + mm.w;
#pragma unroll
    for (int off = 1; off < 64; off <<= 1) part += __shfl_xor(part, off);
    if ((tid & 63) == 0) sred[tid >> 6] = part;
    __syncthreads();
    if (tid == 0) {
        int n = sred[0] + sred[1] + sred[2] + sred[3];
        nsumI[b] = n;
        scaleQ[b] = rsqrtf((float)n) * 1.44269504089f;  // fold log2(e) for exp2 softmax
    }
}

// ---------------- fused conv layer: LN + depthwise conv + pointwise GEMM + residual ----------------
// grid = 512 (b*32 + ltile), block = 512 (8 waves). 32 output rows/block, LN halo +-3.
// W is NOT staged in LDS (L1-resident 32KB); LDS = 18KB -> 4+ blocks/CU.
__global__ __launch_bounds__(512) void k_convlayer(const float* __restrict__ x,
                                                   const u16* __restrict__ Wp,
                                                   const float* __restrict__ dw,
                                                   const float* __restrict__ db,
                                                   const float* __restrict__ pb,
                                                   float* __restrict__ dst) {
    __shared__ alignas(16) u16 lnv[38 * 128];    // LN'ed rows l0-3..l0+34
    __shared__ alignas(16) u16 convt[32 * 128];  // conv output, swizzled A-tile
    int tid = threadIdx.x;
    int w = tid >> 6, l64 = tid & 63;
    int b = blockIdx.x >> 5, lt = blockIdx.x & 31;
    int l0 = lt << 5;
    const float* xb = x + ((size_t)(b << 10)) * 128;

    // LayerNorm rows (wave-cooperative, 2 ch/lane); 8 waves cover 38 rows
    for (int r = w; r < 38; r += 8) {
        int gl = l0 - 3 + r;
        float2 v = {0.f, 0.f};
        bool ok = (gl >= 0) && (gl < 1024);
        if (ok) v = *(const float2*)&xb[(size_t)gl * 128 + (l64 << 1)];
        float s = v.x + v.y, q = v.x * v.x + v.y * v.y;
#pragma unroll
        for (int off = 1; off < 64; off <<= 1) {
            s += __shfl_xor(s, off);
            q += __shfl_xor(q, off);
        }
        float mean = s * (1.0f / 128.0f);
        float var = q * (1.0f / 128.0f) - mean * mean;
        float rs = rsqrtf(var + 1e-5f);
        unsigned int pk = 0;
        if (ok)
            pk = (unsigned int)f2bf((v.x - mean) * rs) | ((unsigned int)f2bf((v.y - mean) * rs) << 16);
        *(unsigned int*)&lnv[r * 128 + (l64 << 1)] = pk;
    }
    __syncthreads();

    // depthwise conv: wave w handles rows w*4..w*4+3, lane = channel pair
    int cp = l64;
    int ls = w;
    float w0[7], w1[7];
#pragma unroll
    for (int k = 0; k < 7; k++) {
        w0[k] = dw[(cp * 2) * 7 + k];
        w1[k] = dw[(cp * 2 + 1) * 7 + k];
    }
    float b0 = db[cp * 2], b1 = db[cp * 2 + 1];
    float v0[10], v1[10];
#pragma unroll
    for (int k = 0; k < 10; k++) {
        unsigned int pk = *(const unsigned int*)&lnv[(ls * 4 + k) * 128 + (cp << 1)];
        v0[k] = bf2f((u16)(pk & 0xffffu));
        v1[k] = bf2f((u16)(pk >> 16));
    }
#pragma unroll
    for (int rr = 0; rr < 4; rr++) {
        int l = ls * 4 + rr;
        float a0 = b0, a1 = b1;
#pragma unroll
        for (int k = 0; k < 7; k++) {
            a0 += v0[rr + k] * w0[k];
            a1 += v1[rr + k] * w1[k];
        }
        int cc = cp >> 2;
        *(unsigned int*)&convt[l * 128 + ((cc ^ (l & 15)) << 3) + ((cp & 3) << 1)] =
            (unsigned int)f2bf(a0) | ((unsigned int)f2bf(a1) << 16);
    }
    __syncthreads();

    // pointwise GEMM 32x128x128: wave w = (mh = w>>2 row-half, nh = w&3 col-quarter)
    int row16 = l64 & 15, g = l64 >> 4;
    int mh = w >> 2, nh = w & 3;
    f32x4 zf = {0.f, 0.f, 0.f, 0.f};
    f32x4 acc[2] = {zf, zf};
#pragma unroll
    for (int kk = 0; kk < 4; kk++) {
        int chunk = ((kk * 4 + g) ^ row16) << 3;
        bf16x8 a = ldb(&convt[(mh * 16 + row16) * 128 + chunk]);
#pragma unroll
        for (int n = 0; n < 2; n++) {
            bf16x8 bfr = ldb(&Wp[(nh * 32 + n * 16 + row16) * 128 + ((kk * 4 + g) << 3)]);
            acc[n] = mfma16(a, bfr, acc[n]);
        }
    }
#pragma unroll
    for (int n = 0; n < 2; n++) {
        int col = nh * 32 + n * 16 + row16;
        float bi = pb[col];
#pragma unroll
        for (int r = 0; r < 4; r++) {
            int row = l0 + mh * 16 + g * 4 + r;
            float val = acc[n][r] + bi + xb[(size_t)row * 128 + col];
            dst[((size_t)(b << 10) + row) * 128 + col] = val;
        }
    }
}

// ---------------- fused LN + GEMM: Y = LN(X) @ W^T -> bf16 (QKV; Q pre-scaled) ----------------
__global__ __launch_bounds__(256) void k_lngemm(const float* __restrict__ x,
                                                const u16* __restrict__ Wb, int wstride,
                                                u16* __restrict__ dstb, int dstride,
                                                const float* __restrict__ scaleQ) {
    __shared__ alignas(16) u16 sX[64 * 128];
    const u16* Wp = Wb + (size_t)blockIdx.y * wstride;
    dstb += (size_t)blockIdx.y * dstride;
    float qs = (blockIdx.y == 0) ? scaleQ[blockIdx.x >> 4] : 1.0f;
    int tid = threadIdx.x;
    int w = tid >> 6, l64 = tid & 63;
    int rbase = blockIdx.x * 64;

    for (int r = w; r < 64; r += 4) {
        float2 v = *(const float2*)&x[((size_t)(rbase + r)) * 128 + (l64 << 1)];
        float s = v.x + v.y, q = v.x * v.x + v.y * v.y;
#pragma unroll
        for (int off = 1; off < 64; off <<= 1) {
            s += __shfl_xor(s, off);
            q += __shfl_xor(q, off);
        }
        float mean = s * (1.0f / 128.0f);
        float var = q * (1.0f / 128.0f) - mean * mean;
        float rs = rsqrtf(var + 1e-5f);
        unsigned int pk = (unsigned int)f2bf((v.x - mean) * rs) |
                          ((unsigned int)f2bf((v.y - mean) * rs) << 16);
        int cc = l64 >> 2;
        *(unsigned int*)&sX[r * 128 + ((cc ^ (r & 15)) << 3) + ((l64 & 3) << 1)] = pk;
    }
    __syncthreads();

    int row16 = l64 & 15, g = l64 >> 4;
    f32x4 zf = {0.f, 0.f, 0.f, 0.f};
    f32x4 acc[8];
#pragma unroll
    for (int n = 0; n < 8; n++) acc[n] = zf;
#pragma unroll
    for (int kk = 0; kk < 4; kk++) {
        int chunk = ((kk * 4 + g) ^ row16) << 3;
        bf16x8 a = ldb(&sX[(w * 16 + row16) * 128 + chunk]);
#pragma unroll
        for (int n = 0; n < 8; n++) {
            bf16x8 bfr = ldb(&Wp[(n * 16 + row16) * 128 + ((kk * 4 + g) << 3)]);
            acc[n] = mfma16(a, bfr, acc[n]);
        }
    }
    int r0 = rbase + w * 16 + g * 4;
#pragma unroll
    for (int n = 0; n < 8; n++) {
        int col = n * 16 + row16;
#pragma unroll
        for (int r = 0; r < 4; r++)
            dstb[(size_t)(r0 + r) * 128 + col] = f2bf(acc[n][r] * qs);
    }
}

// ---------------- fused wo-GEMM + residual + LN + ff-GEMM + residual ----------------
__global__ __launch_bounds__(256) void k_wolnff(const u16* __restrict__ X,
                                                const u16* __restrict__ Wo,
                                                const u16* __restrict__ Wff,
                                                const float* __restrict__ res,
                                                float* __restrict__ dst) {
    __shared__ alignas(16) u16 sX[64 * 128];
    int tid = threadIdx.x;
    int w = tid >> 6, l64 = tid & 63;
    int rbase = blockIdx.x * 64;
#pragma unroll
    for (int j = 0; j < 4; j++) {
        int e = j * 256 + tid;
        int r = e >> 4, cc = e & 15;
        *(u32x4*)&sX[r * 128 + ((cc ^ (r & 15)) << 3)] =
            *(const u32x4*)&X[((rbase + r) << 7) + (cc << 3)];
    }
    __syncthreads();

    int row16 = l64 & 15, g = l64 >> 4;
    f32x4 zf = {0.f, 0.f, 0.f, 0.f};
    f32x4 acc[8];
#pragma unroll
    for (int n = 0; n < 8; n++) acc[n] = zf;
#pragma unroll
    for (int kk = 0; kk < 4; kk++) {
        int chunk = ((kk * 4 + g) ^ row16) << 3;
        bf16x8 a = ldb(&sX[(w * 16 + row16) * 128 + chunk]);
#pragma unroll
        for (int n = 0; n < 8; n++) {
            bf16x8 bfr = ldb(&Wo[(n * 16 + row16) * 128 + ((kk * 4 + g) << 3)]);
            acc[n] = mfma16(a, bfr, acc[n]);
        }
    }
    f32x4 vals[8];
#pragma unroll
    for (int n = 0; n < 8; n++) {
        int col = n * 16 + row16;
#pragma unroll
        for (int r = 0; r < 4; r++)
            vals[n][r] = acc[n][r] + res[(size_t)(rbase + w * 16 + g * 4 + r) * 128 + col];
    }
    float mean[4], rstd[4];
#pragma unroll
    for (int r = 0; r < 4; r++) {
        float s = 0.f, q = 0.f;
#pragma unroll
        for (int n = 0; n < 8; n++) {
            s += vals[n][r];
            q += vals[n][r] * vals[n][r];
        }
#pragma unroll
        for (int off = 1; off < 16; off <<= 1) {
            s += __shfl_xor(s, off);
            q += __shfl_xor(q, off);
        }
        mean[r] = s * (1.0f / 128.0f);
        float var = q * (1.0f / 128.0f) - mean[r] * mean[r];
        rstd[r] = rsqrtf(var + 1e-5f);
    }
    __syncthreads();
#pragma unroll
    for (int n = 0; n < 8; n++) {
        int col = n * 16 + row16;
        int cc = col >> 3;
#pragma unroll
        for (int r = 0; r < 4; r++) {
            int row = w * 16 + g * 4 + r;
            sX[row * 128 + ((cc ^ (row & 15)) << 3) + (row16 & 7)] =
                f2bf((vals[n][r] - mean[r]) * rstd[r]);
        }
    }
    __syncthreads();
    f32x4 acc2[8];
#pragma unroll
    for (int n = 0; n < 8; n++) acc2[n] = zf;
#pragma unroll
    for (int kk = 0; kk < 4; kk++) {
        int chunk = ((kk * 4 + g) ^ row16) << 3;
        bf16x8 a = ldb(&sX[(w * 16 + row16) * 128 + chunk]);
#pragma unroll
        for (int n = 0; n < 8; n++) {
            bf16x8 bfr = ldb(&Wff[(n * 16 + row16) * 128 + ((kk * 4 + g) << 3)]);
            acc2[n] = mfma16(a, bfr, acc2[n]);
        }
    }
#pragma unroll
    for (int n = 0; n < 8; n++) {
        int col = n * 16 + row16;
#pragma unroll
        for (int r = 0; r < 4; r++)
            dst[(size_t)(rbase + w * 16 + g * 4 + r) * 128 + col] = vals[n][r] + acc2[n][r];
    }
}

// ---------------- fused attention (r5 structure + XCD affinity + prescaled Q) ----------------
// grid = 1024: bh = blockIdx & 127, qblk = blockIdx >> 7 (same-bh blocks share XCD)
// block = 512 (8 waves x 16 q-rows)
// S^T = mfma(A=K, B=Qs): lane: q = l&15, k = ktile*16 + (l>>4)*4 + reg
// PV:  O^T = mfma(A=Vt, B=P): lane: q = l&15, d = (l>>4)*4 + reg
#define LOAD_VF(P)                                                                             \
    bf16x8 vf;                                                                                 \
    {                                                                                          \
        const u16* vp = &sVt[row16 * 1032 + (P) * 32 + (g << 2)];                              \
        union { u16x4 h[2]; u16x8 v8; } uu;                                                    \
        uu.h[0] = *(const u16x4*)vp;                                                           \
        uu.h[1] = *(const u16x4*)(vp + 16);                                                    \
        vf = __builtin_bit_cast(bf16x8, uu.v8);                                                \
    }

#define SM_PV(SV)                                                                              \
    {                                                                                          \
        float pj[8];                                                                           \
        _Pragma("unroll") for (int jj = 0; jj < 8; jj++) pj[jj] = exp2f(SV[jj]);               \
        lrun += ((pj[0] + pj[1]) + (pj[2] + pj[3])) + ((pj[4] + pj[5]) + (pj[6] + pj[7]));     \
        bf16x8 pa;                                                                             \
        _Pragma("unroll") for (int jj = 0; jj < 8; jj++) pa[jj] = (__bf16)pj[jj];              \
        oacc = mfma16(vf, pa, oacc);                                                           \
    }

__global__ __launch_bounds__(512) void k_attn(const u16* __restrict__ Qg, const u16* __restrict__ Kg,
                                              const u16* __restrict__ Vg,
                                              const int* __restrict__ nsumI,
                                              u16* __restrict__ Og) {
    __shared__ alignas(16) u16 sVt[16 * 1032];  // 33KB: [d][m], row-padded +8
    int tid = threadIdx.x;
    int w = tid >> 6, l = tid & 63;
    int bh = blockIdx.x & 127;
    int qblk = blockIdx.x >> 7;
    int b = bh >> 3, h = bh & 7;
    int row16 = l & 15, g = l >> 4;

    const u16* kg = Kg + (size_t)(b << 10) * 128 + (h << 4);
    const u16* vg = Vg + (size_t)(b << 10) * 128 + (h << 4);
#pragma unroll
    for (int j = 0; j < 4; j++) {
        int e = j * 512 + tid;
        int m = e >> 1, half = e & 1;
        u32x4 vv = *(const u32x4*)&vg[m * 128 + half * 8];
        union { u32x4 q; u16 s[8]; } u;
        u.q = vv;
#pragma unroll
        for (int jj = 0; jj < 8; jj++) sVt[(half * 8 + jj) * 1032 + m] = u.s[jj];
    }
    __syncthreads();
    int nsum = nsumI[b];

    int qbase = qblk * 128 + w * 16;
    u16x8 z8 = {0, 0, 0, 0, 0, 0, 0, 0};
    const bf16x8 zb = __builtin_bit_cast(bf16x8, z8);
    f32x4 zf = {0.f, 0.f, 0.f, 0.f};

    bool rowv = (qbase + row16) < nsum;
    bf16x8 qf = zb;
    if (rowv && g < 2)  // pre-scaled Q (rsqrt(nsum)*log2e folded); invalid rows: S=0 -> P=1
        qf = ldb(&Qg[(size_t)((b << 10) + qbase + row16) * 128 + (h << 4) + (g << 3)]);
    f32x4 oacc = zf;
    float lrun = 0.0f;

    int p = 0;
    if (qbase < nsum) {  // wave has at least one valid q-row
        int full = nsum >> 5;
        for (; p < full; p++) {
            bf16x8 kf0 = zb, kf1 = zb;
            if (g < 2) {
                kf0 = ldb(&kg[(size_t)((p << 5) + row16) * 128 + (g << 3)]);
                kf1 = ldb(&kg[(size_t)((p << 5) + 16 + row16) * 128 + (g << 3)]);
            }
            LOAD_VF(p)
            f32x4 s0 = mfma16(kf0, qf, zf);
            f32x4 s1 = mfma16(kf1, qf, zf);
            float sv[8];
#pragma unroll
            for (int r = 0; r < 4; r++) {
                sv[r] = s0[r];
                sv[4 + r] = s1[r];
            }
            SM_PV(sv)
        }
        if (nsum & 31) {  // one partial pair
            bf16x8 kf0 = zb, kf1 = zb;
            if (g < 2) {
                kf0 = ldb(&kg[(size_t)((p << 5) + row16) * 128 + (g << 3)]);
                kf1 = ldb(&kg[(size_t)((p << 5) + 16 + row16) * 128 + (g << 3)]);
            }
            LOAD_VF(p)
            int kb_ = p << 5;
            f32x4 s0 = mfma16(kf0, qf, zf);
            f32x4 s1 = mfma16(kf1, qf, zf);
            float negfill = rowv ? -1.0e30f : 0.0f;  // invalid rows: P=1 on all cols
            float sv[8];
#pragma unroll
            for (int r = 0; r < 4; r++) {
                sv[r] = ((kb_ + (g << 2) + r) < nsum) ? s0[r] : negfill;
                sv[4 + r] = ((kb_ + 16 + (g << 2) + r) < nsum) ? s1[r] : negfill;
            }
            SM_PV(sv)
            p++;
        }
    }
    if (qbase + 16 > nsum && p < 32) {  // waves holding invalid rows: constant P tail
        int ntail = 32 - p;
        __bf16 vcst = rowv ? (__bf16)0.0f : (__bf16)1.0f;
        bf16x8 pt = {vcst, vcst, vcst, vcst, vcst, vcst, vcst, vcst};
        if (!rowv) lrun += 8.0f * (float)ntail;
        for (; p < 32; p++) {
            LOAD_VF(p)
            oacc = mfma16(vf, pt, oacc);
        }
    }

    float lr = lrun;
    lr += __shfl_xor(lr, 16);
    lr += __shfl_xor(lr, 32);
    float inv = 1.0f / lr;
    u16x4 ov;
#pragma unroll
    for (int r = 0; r < 4; r++) ov[r] = f2bf(oacc[r] * inv);
    int q = qbase + row16;
    *(u16x4*)&Og[(size_t)((b << 10) + q) * 128 + (h << 4) + (g << 2)] = ov;
}

extern "C" void kernel_launch(void* const* d_in, const int* in_sizes, int n_in,
                              void* d_out, int out_size, void* d_ws, size_t ws_size,
                              hipStream_t stream) {
    const float* emb     = (const float*)d_in[0];
    const int*   mask    = (const int*)d_in[1];
    const float* depth_w = (const float*)d_in[2];
    const float* depth_b = (const float*)d_in[3];
    const float* pt_w    = (const float*)d_in[4];
    const float* pt_b    = (const float*)d_in[5];
    const float* wq      = (const float*)d_in[6];
    const float* wk      = (const float*)d_in[7];
    const float* wv      = (const float*)d_in[8];
    const float* wo      = (const float*)d_in[9];
    const float* wff     = (const float*)d_in[10];
    float* out = (float*)d_out;
    char* ws = (char*)d_ws;

    float* f32a = (float*)(ws + 0);             // 8.4 MB conv ping-pong
    u16* qb    = (u16*)(ws + 8388608);
    u16* kb    = (u16*)(ws + 12582912);
    u16* vb    = (u16*)(ws + 16777216);
    u16* attnb = (u16*)(ws + 20971520);
    u16* wb    = (u16*)(ws + 25165824);
    u16* ptwb = wb;
    u16* wqb = wb + 65536;
    u16* wob = wb + 114688;
    u16* wffb = wb + 131072;
    int*   nsumI  = (int*)(ws + 25460736);
    float* scaleQ = (float*)(ws + 25460800);

    k_cvtw<<<576, 256, 0, stream>>>(pt_w, wq, wk, wv, wo, wff, wb);
    k_nsum<<<16, 256, 0, stream>>>(mask, nsumI, scaleQ);

    // conv layers ping-pong: emb -> f32a -> out -> f32a -> out
    const float* src[4] = {emb, f32a, out, f32a};
    float* dst[4] = {f32a, out, f32a, out};
    for (int i = 0; i < 4; i++) {
        k_convlayer<<<512, 512, 0, stream>>>(src[i], ptwb + i * 16384, depth_w + i * 896,
                                             depth_b + i * 128, pt_b + i * 128, dst[i]);
    }
    // LN + QKV (batched over y); Q pre-scaled by rsqrt(nsum)*log2e
    {
        dim3 g3(256, 3);
        k_lngemm<<<g3, 256, 0, stream>>>(out, wqb, 16384, qb, 2097152, scaleQ);
    }
    k_attn<<<1024, 512, 0, stream>>>(qb, kb, vb, nsumI, attnb);
    // wo GEMM + residual + LN + ff GEMM + residual -> out
    k_wolnff<<<256, 256, 0, stream>>>(attnb, wob, wffb, out, out);
}

// Round 10
// 116.611 us; speedup vs baseline: 1.2067x; 1.2067x over previous
//
#include <hip/hip_runtime.h>

typedef unsigned short u16;
typedef float f32x4 __attribute__((ext_vector_type(4)));
typedef unsigned int u32x4 __attribute__((ext_vector_type(4)));
typedef unsigned short u16x4 __attribute__((ext_vector_type(4)));
typedef unsigned short u16x8 __attribute__((ext_vector_type(8)));
typedef __bf16 bf16x8 __attribute__((ext_vector_type(8)));

#define DEVFN static __device__ __forceinline__

DEVFN float bf2f(u16 u) {
    unsigned int i = ((unsigned int)u) << 16;
    float f;
    __builtin_memcpy(&f, &i, 4);
    return f;
}
DEVFN u16 f2bf(float f) {
    unsigned int i;
    __builtin_memcpy(&i, &f, 4);
    unsigned int r = i + 0x7fffu + ((i >> 16) & 1u);
    return (u16)(r >> 16);
}

DEVFN bf16x8 ldb(const u16* p) { return __builtin_bit_cast(bf16x8, *(const u16x8*)p); }

// 16x16x32: C/D: col=lane&15 (Brow), row=(lane>>4)*4+reg (Arow)  (HW-verified r2)
DEVFN f32x4 mfma16(bf16x8 a, bf16x8 b, f32x4 c) {
    return __builtin_amdgcn_mfma_f32_16x16x32_bf16(a, b, c, 0, 0, 0);
}

// raw v_exp_f32: skips the compiler's denormal-range fixup (~6 VALU -> 1 trans).
// Safe here: args are either |x| < ~4 or -1e30 (raw op returns 0).
#if __has_builtin(__builtin_amdgcn_exp2f)
DEVFN float ex2(float x) { return __builtin_amdgcn_exp2f(x); }
#else
DEVFN float ex2(float x) { return exp2f(x); }
#endif

// ---------------- weight convert: fp32 -> bf16 ----------------
__global__ __launch_bounds__(256) void k_cvtw(const float* __restrict__ pt,
                                              const float* __restrict__ q,
                                              const float* __restrict__ k,
                                              const float* __restrict__ v,
                                              const float* __restrict__ o,
                                              const float* __restrict__ f,
                                              u16* __restrict__ dst) {
    int i = blockIdx.x * 256 + threadIdx.x;  // grid covers exactly 147456
    const float* s;
    int off;
    if (i < 65536)       { s = pt; off = i; }
    else if (i < 81920)  { s = q;  off = i - 65536; }
    else if (i < 98304)  { s = k;  off = i - 81920; }
    else if (i < 114688) { s = v;  off = i - 98304; }
    else if (i < 131072) { s = o;  off = i - 114688; }
    else                 { s = f;  off = i - 131072; }
    dst[i] = f2bf(s[off]);
}

// ---------------- per-batch mask sum + Q scale ----------------
__global__ __launch_bounds__(256) void k_nsum(const int* __restrict__ mask,
                                              int* __restrict__ nsumI,
                                              float* __restrict__ scaleQ) {
    __shared__ int sred[4];
    int tid = threadIdx.x, b = blockIdx.x;
    int4 mm = *(const int4*)&mask[(b << 10) + tid * 4];
    int part = mm.x + mm.y + mm.z + mm.w;
#pragma unroll
    for (int off = 1; off < 64; off <<= 1) part += __shfl_xor(part, off);
    if ((tid & 63) == 0) sred[tid >> 6] = part;
    __syncthreads();
    if (tid == 0) {
        int n = sred[0] + sred[1] + sred[2] + sred[3];
        nsumI[b] = n;
        scaleQ[b] = rsqrtf((float)n) * 1.44269504089f;  // fold log2(e) for exp2 softmax
    }
}

// ---------------- fused conv layer: LN + depthwise conv + pointwise GEMM + residual ----------------
// grid = 512 (b*32 + ltile), block = 256 (4 waves). LDS 50KB -> 3 blocks/CU.
__global__ __launch_bounds__(256) void k_convlayer(const float* __restrict__ x,
                                                   const u16* __restrict__ Wp,
                                                   const float* __restrict__ dw,
                                                   const float* __restrict__ db,
                                                   const float* __restrict__ pb,
                                                   float* __restrict__ dst) {
    __shared__ alignas(16) u16 lnv[38 * 128];    // LN'ed rows l0-3..l0+34
    __shared__ alignas(16) u16 convt[32 * 128];  // conv output, swizzled A-tile
    __shared__ alignas(16) u16 sW[128 * 128];    // pointwise W, swizzled
    int tid = threadIdx.x;
    int w = tid >> 6, l64 = tid & 63;
    int b = blockIdx.x >> 5, lt = blockIdx.x & 31;
    int l0 = lt << 5;
    const float* xb = x + ((size_t)(b << 10)) * 128;

#pragma unroll
    for (int j = 0; j < 8; j++) {
        int e = j * 256 + tid;
        int r = e >> 4, cc = e & 15;
        *(u32x4*)&sW[r * 128 + ((cc ^ (r & 15)) << 3)] = *(const u32x4*)&Wp[(r << 7) + (cc << 3)];
    }

    for (int r = w; r < 38; r += 4) {
        int gl = l0 - 3 + r;
        float2 v = {0.f, 0.f};
        bool ok = (gl >= 0) && (gl < 1024);
        if (ok) v = *(const float2*)&xb[(size_t)gl * 128 + (l64 << 1)];
        float s = v.x + v.y, q = v.x * v.x + v.y * v.y;
#pragma unroll
        for (int off = 1; off < 64; off <<= 1) {
            s += __shfl_xor(s, off);
            q += __shfl_xor(q, off);
        }
        float mean = s * (1.0f / 128.0f);
        float var = q * (1.0f / 128.0f) - mean * mean;
        float rs = rsqrtf(var + 1e-5f);
        unsigned int pk = 0;
        if (ok)
            pk = (unsigned int)f2bf((v.x - mean) * rs) | ((unsigned int)f2bf((v.y - mean) * rs) << 16);
        *(unsigned int*)&lnv[r * 128 + (l64 << 1)] = pk;
    }
    __syncthreads();

    // depthwise conv, sliding window: 14 LDS reads per thread, values kept in regs
    int cp = tid & 63;
    int ls = tid >> 6;
    float w0[7], w1[7];
#pragma unroll
    for (int k = 0; k < 7; k++) {
        w0[k] = dw[(cp * 2) * 7 + k];
        w1[k] = dw[(cp * 2 + 1) * 7 + k];
    }
    float b0 = db[cp * 2], b1 = db[cp * 2 + 1];
    float v0[14], v1[14];
#pragma unroll
    for (int k = 0; k < 14; k++) {
        unsigned int pk = *(const unsigned int*)&lnv[(ls * 8 + k) * 128 + (cp << 1)];
        v0[k] = bf2f((u16)(pk & 0xffffu));
        v1[k] = bf2f((u16)(pk >> 16));
    }
#pragma unroll
    for (int rr = 0; rr < 8; rr++) {
        int l = ls * 8 + rr;
        float a0 = b0, a1 = b1;
#pragma unroll
        for (int k = 0; k < 7; k++) {
            a0 += v0[rr + k] * w0[k];
            a1 += v1[rr + k] * w1[k];
        }
        int cc = cp >> 2;
        *(unsigned int*)&convt[l * 128 + ((cc ^ (l & 15)) << 3) + ((cp & 3) << 1)] =
            (unsigned int)f2bf(a0) | ((unsigned int)f2bf(a1) << 16);
    }
    __syncthreads();

    // pointwise GEMM 32x128x128: wave w = (mh = w>>1, nh = w&1)
    int row16 = l64 & 15, g = l64 >> 4;
    int mh = w >> 1, nh = w & 1;
    f32x4 zf = {0.f, 0.f, 0.f, 0.f};
    f32x4 acc[4] = {zf, zf, zf, zf};
#pragma unroll
    for (int kk = 0; kk < 4; kk++) {
        int chunk = ((kk * 4 + g) ^ row16) << 3;
        bf16x8 a = ldb(&convt[(mh * 16 + row16) * 128 + chunk]);
#pragma unroll
        for (int n = 0; n < 4; n++) {
            bf16x8 bfr = ldb(&sW[(nh * 64 + n * 16 + row16) * 128 + chunk]);
            acc[n] = mfma16(a, bfr, acc[n]);
        }
    }
#pragma unroll
    for (int n = 0; n < 4; n++) {
        int col = nh * 64 + n * 16 + row16;
        float bi = pb[col];
#pragma unroll
        for (int r = 0; r < 4; r++) {
            int row = l0 + mh * 16 + g * 4 + r;
            float val = acc[n][r] + bi + xb[(size_t)row * 128 + col];
            dst[((size_t)(b << 10) + row) * 128 + col] = val;
        }
    }
}

// ---------------- fused LN + GEMM: Y = LN(X) @ W^T -> bf16 (QKV; Q pre-scaled) ----------------
__global__ __launch_bounds__(256) void k_lngemm(const float* __restrict__ x,
                                                const u16* __restrict__ Wb, int wstride,
                                                u16* __restrict__ dstb, int dstride,
                                                const float* __restrict__ scaleQ) {
    __shared__ alignas(16) u16 sX[64 * 128];
    __shared__ alignas(16) u16 sW[128 * 128];
    const u16* Wp = Wb + (size_t)blockIdx.y * wstride;
    dstb += (size_t)blockIdx.y * dstride;
    float qs = (blockIdx.y == 0) ? scaleQ[blockIdx.x >> 4] : 1.0f;
    int tid = threadIdx.x;
    int w = tid >> 6, l64 = tid & 63;
    int rbase = blockIdx.x * 64;

#pragma unroll
    for (int j = 0; j < 8; j++) {
        int e = j * 256 + tid;
        int r = e >> 4, cc = e & 15;
        *(u32x4*)&sW[r * 128 + ((cc ^ (r & 15)) << 3)] = *(const u32x4*)&Wp[(r << 7) + (cc << 3)];
    }
    for (int r = w; r < 64; r += 4) {
        float2 v = *(const float2*)&x[((size_t)(rbase + r)) * 128 + (l64 << 1)];
        float s = v.x + v.y, q = v.x * v.x + v.y * v.y;
#pragma unroll
        for (int off = 1; off < 64; off <<= 1) {
            s += __shfl_xor(s, off);
            q += __shfl_xor(q, off);
        }
        float mean = s * (1.0f / 128.0f);
        float var = q * (1.0f / 128.0f) - mean * mean;
        float rs = rsqrtf(var + 1e-5f);
        unsigned int pk = (unsigned int)f2bf((v.x - mean) * rs) |
                          ((unsigned int)f2bf((v.y - mean) * rs) << 16);
        int cc = l64 >> 2;
        *(unsigned int*)&sX[r * 128 + ((cc ^ (r & 15)) << 3) + ((l64 & 3) << 1)] = pk;
    }
    __syncthreads();

    int row16 = l64 & 15, g = l64 >> 4;
    f32x4 zf = {0.f, 0.f, 0.f, 0.f};
    f32x4 acc[8];
#pragma unroll
    for (int n = 0; n < 8; n++) acc[n] = zf;
#pragma unroll
    for (int kk = 0; kk < 4; kk++) {
        int chunk = ((kk * 4 + g) ^ row16) << 3;
        bf16x8 a = ldb(&sX[(w * 16 + row16) * 128 + chunk]);
#pragma unroll
        for (int n = 0; n < 8; n++) {
            bf16x8 bfr = ldb(&sW[(n * 16 + row16) * 128 + chunk]);
            acc[n] = mfma16(a, bfr, acc[n]);
        }
    }
    int r0 = rbase + w * 16 + g * 4;
#pragma unroll
    for (int n = 0; n < 8; n++) {
        int col = n * 16 + row16;
#pragma unroll
        for (int r = 0; r < 4; r++)
            dstb[(size_t)(r0 + r) * 128 + col] = f2bf(acc[n][r] * qs);
    }
}

// ---------------- fused wo-GEMM + residual + LN + ff-GEMM + residual ----------------
__global__ __launch_bounds__(256) void k_wolnff(const u16* __restrict__ X,
                                                const u16* __restrict__ Wo,
                                                const u16* __restrict__ Wff,
                                                const float* __restrict__ res,
                                                float* __restrict__ dst) {
    __shared__ alignas(16) u16 sX[64 * 128];
    __shared__ alignas(16) u16 sW1[128 * 128];
    __shared__ alignas(16) u16 sW2[128 * 128];
    int tid = threadIdx.x;
    int w = tid >> 6, l64 = tid & 63;
    int rbase = blockIdx.x * 64;
#pragma unroll
    for (int j = 0; j < 8; j++) {
        int e = j * 256 + tid;
        int r = e >> 4, cc = e & 15;
        int sw = ((cc ^ (r & 15)) << 3);
        *(u32x4*)&sW1[r * 128 + sw] = *(const u32x4*)&Wo[(r << 7) + (cc << 3)];
        *(u32x4*)&sW2[r * 128 + sw] = *(const u32x4*)&Wff[(r << 7) + (cc << 3)];
    }
#pragma unroll
    for (int j = 0; j < 4; j++) {
        int e = j * 256 + tid;
        int r = e >> 4, cc = e & 15;
        *(u32x4*)&sX[r * 128 + ((cc ^ (r & 15)) << 3)] =
            *(const u32x4*)&X[((rbase + r) << 7) + (cc << 3)];
    }
    __syncthreads();

    int row16 = l64 & 15, g = l64 >> 4;
    f32x4 zf = {0.f, 0.f, 0.f, 0.f};
    f32x4 acc[8];
#pragma unroll
    for (int n = 0; n < 8; n++) acc[n] = zf;
#pragma unroll
    for (int kk = 0; kk < 4; kk++) {
        int chunk = ((kk * 4 + g) ^ row16) << 3;
        bf16x8 a = ldb(&sX[(w * 16 + row16) * 128 + chunk]);
#pragma unroll
        for (int n = 0; n < 8; n++) {
            bf16x8 bfr = ldb(&sW1[(n * 16 + row16) * 128 + chunk]);
            acc[n] = mfma16(a, bfr, acc[n]);
        }
    }
    f32x4 vals[8];
#pragma unroll
    for (int n = 0; n < 8; n++) {
        int col = n * 16 + row16;
#pragma unroll
        for (int r = 0; r < 4; r++)
            vals[n][r] = acc[n][r] + res[(size_t)(rbase + w * 16 + g * 4 + r) * 128 + col];
    }
    float mean[4], rstd[4];
#pragma unroll
    for (int r = 0; r < 4; r++) {
        float s = 0.f, q = 0.f;
#pragma unroll
        for (int n = 0; n < 8; n++) {
            s += vals[n][r];
            q += vals[n][r] * vals[n][r];
        }
#pragma unroll
        for (int off = 1; off < 16; off <<= 1) {
            s += __shfl_xor(s, off);
            q += __shfl_xor(q, off);
        }
        mean[r] = s * (1.0f / 128.0f);
        float var = q * (1.0f / 128.0f) - mean[r] * mean[r];
        rstd[r] = rsqrtf(var + 1e-5f);
    }
    __syncthreads();
#pragma unroll
    for (int n = 0; n < 8; n++) {
        int col = n * 16 + row16;
        int cc = col >> 3;
#pragma unroll
        for (int r = 0; r < 4; r++) {
            int row = w * 16 + g * 4 + r;
            sX[row * 128 + ((cc ^ (row & 15)) << 3) + (row16 & 7)] =
                f2bf((vals[n][r] - mean[r]) * rstd[r]);
        }
    }
    __syncthreads();
    f32x4 acc2[8];
#pragma unroll
    for (int n = 0; n < 8; n++) acc2[n] = zf;
#pragma unroll
    for (int kk = 0; kk < 4; kk++) {
        int chunk = ((kk * 4 + g) ^ row16) << 3;
        bf16x8 a = ldb(&sX[(w * 16 + row16) * 128 + chunk]);
#pragma unroll
        for (int n = 0; n < 8; n++) {
            bf16x8 bfr = ldb(&sW2[(n * 16 + row16) * 128 + chunk]);
            acc2[n] = mfma16(a, bfr, acc2[n]);
        }
    }
#pragma unroll
    for (int n = 0; n < 8; n++) {
        int col = n * 16 + row16;
#pragma unroll
        for (int r = 0; r < 4; r++)
            dst[(size_t)(rbase + w * 16 + g * 4 + r) * 128 + col] = vals[n][r] + acc2[n][r];
    }
}

// ---------------- fused attention (r5 structure + prescaled Q + raw v_exp) ----------------
// grid = 1024: bh = blockIdx >> 3, qblk = blockIdx & 7 ; block = 512 (8 waves x 16 q-rows)
// S^T = mfma(A=K, B=Qs): lane: q = l&15, k = ktile*16 + (l>>4)*4 + reg
// PV:  O^T = mfma(A=Vt, B=P): lane: q = l&15, d = (l>>4)*4 + reg
#define LOAD_VF(P)                                                                             \
    bf16x8 vf;                                                                                 \
    {                                                                                          \
        const u16* vp = &sVt[row16 * 1032 + (P) * 32 + (g << 2)];                              \
        union { u16x4 h[2]; u16x8 v8; } uu;                                                    \
        uu.h[0] = *(const u16x4*)vp;                                                           \
        uu.h[1] = *(const u16x4*)(vp + 16);                                                    \
        vf = __builtin_bit_cast(bf16x8, uu.v8);                                                \
    }

#define SM_PV(SV)                                                                              \
    {                                                                                          \
        float p0 = ex2(SV[0]), p1 = ex2(SV[1]), p2 = ex2(SV[2]), p3 = ex2(SV[3]);              \
        float p4 = ex2(SV[4]), p5 = ex2(SV[5]), p6 = ex2(SV[6]), p7 = ex2(SV[7]);              \
        lrun += ((p0 + p1) + (p2 + p3)) + ((p4 + p5) + (p6 + p7));                             \
        bf16x8 pa = {(__bf16)p0, (__bf16)p1, (__bf16)p2, (__bf16)p3,                           \
                     (__bf16)p4, (__bf16)p5, (__bf16)p6, (__bf16)p7};                          \
        oacc = mfma16(vf, pa, oacc);                                                           \
    }

__global__ __launch_bounds__(512) void k_attn(const u16* __restrict__ Qg, const u16* __restrict__ Kg,
                                              const u16* __restrict__ Vg,
                                              const int* __restrict__ nsumI,
                                              u16* __restrict__ Og) {
    __shared__ alignas(16) u16 sVt[16 * 1032];  // 33KB: [d][m], row-padded +8
    int tid = threadIdx.x;
    int w = tid >> 6, l = tid & 63;
    int bh = blockIdx.x >> 3;
    int qblk = blockIdx.x & 7;
    int b = bh >> 3, h = bh & 7;
    int row16 = l & 15, g = l >> 4;

    const u16* kg = Kg + (size_t)(b << 10) * 128 + (h << 4);
    const u16* vg = Vg + (size_t)(b << 10) * 128 + (h << 4);
#pragma unroll
    for (int j = 0; j < 4; j++) {
        int e = j * 512 + tid;
        int m = e >> 1, half = e & 1;
        u32x4 vv = *(const u32x4*)&vg[m * 128 + half * 8];
        union { u32x4 q; u16 s[8]; } u;
        u.q = vv;
#pragma unroll
        for (int jj = 0; jj < 8; jj++) sVt[(half * 8 + jj) * 1032 + m] = u.s[jj];
    }
    __syncthreads();
    int nsum = nsumI[b];

    int qbase = qblk * 128 + w * 16;
    u16x8 z8 = {0, 0, 0, 0, 0, 0, 0, 0};
    const bf16x8 zb = __builtin_bit_cast(bf16x8, z8);
    f32x4 zf = {0.f, 0.f, 0.f, 0.f};

    bool rowv = (qbase + row16) < nsum;
    bf16x8 qf = zb;
    if (rowv && g < 2)  // pre-scaled Q (rsqrt(nsum)*log2e folded); invalid rows: S=0 -> P=1
        qf = ldb(&Qg[(size_t)((b << 10) + qbase + row16) * 128 + (h << 4) + (g << 3)]);
    f32x4 oacc = zf;
    float lrun = 0.0f;

    const u16* kl = kg + row16 * 128 + (g << 3);  // per-lane K ptr (g<2 lanes), +8KB/pair
    int p = 0;
    if (qbase < nsum) {  // wave has at least one valid q-row
        int full = nsum >> 5;
        for (; p < full; p++) {
            bf16x8 kf0 = zb, kf1 = zb;
            if (g < 2) {
                kf0 = ldb(kl);
                kf1 = ldb(kl + 2048);
            }
            LOAD_VF(p)
            kl += 4096;
            f32x4 s0 = mfma16(kf0, qf, zf);
            f32x4 s1 = mfma16(kf1, qf, zf);
            float sv[8];
#pragma unroll
            for (int r = 0; r < 4; r++) {
                sv[r] = s0[r];
                sv[4 + r] = s1[r];
            }
            SM_PV(sv)
        }
        if (nsum & 31) {  // one partial pair
            bf16x8 kf0 = zb, kf1 = zb;
            if (g < 2) {
                kf0 = ldb(kl);
                kf1 = ldb(kl + 2048);
            }
            LOAD_VF(p)
            int kb_ = p << 5;
            f32x4 s0 = mfma16(kf0, qf, zf);
            f32x4 s1 = mfma16(kf1, qf, zf);
            float negfill = rowv ? -1.0e30f : 0.0f;  // invalid rows: P=1 on all cols
            float sv[8];
#pragma unroll
            for (int r = 0; r < 4; r++) {
                sv[r] = ((kb_ + (g << 2) + r) < nsum) ? s0[r] : negfill;
                sv[4 + r] = ((kb_ + 16 + (g << 2) + r) < nsum) ? s1[r] : negfill;
            }
            SM_PV(sv)
            p++;
        }
    }
    if (qbase + 16 > nsum && p < 32) {  // waves holding invalid rows: constant P tail
        int ntail = 32 - p;
        __bf16 vcst = rowv ? (__bf16)0.0f : (__bf16)1.0f;
        bf16x8 pt = {vcst, vcst, vcst, vcst, vcst, vcst, vcst, vcst};
        if (!rowv) lrun += 8.0f * (float)ntail;
        for (; p < 32; p++) {
            LOAD_VF(p)
            oacc = mfma16(vf, pt, oacc);
        }
    }

    float lr = lrun;
    lr += __shfl_xor(lr, 16);
    lr += __shfl_xor(lr, 32);
    float inv = 1.0f / lr;
    u16x4 ov;
#pragma unroll
    for (int r = 0; r < 4; r++) ov[r] = f2bf(oacc[r] * inv);
    int q = qbase + row16;
    *(u16x4*)&Og[(size_t)((b << 10) + q) * 128 + (h << 4) + (g << 2)] = ov;
}

extern "C" void kernel_launch(void* const* d_in, const int* in_sizes, int n_in,
                              void* d_out, int out_size, void* d_ws, size_t ws_size,
                              hipStream_t stream) {
    const float* emb     = (const float*)d_in[0];
    const int*   mask    = (const int*)d_in[1];
    const float* depth_w = (const float*)d_in[2];
    const float* depth_b = (const float*)d_in[3];
    const float* pt_w    = (const float*)d_in[4];
    const float* pt_b    = (const float*)d_in[5];
    const float* wq      = (const float*)d_in[6];
    const float* wk      = (const float*)d_in[7];
    const float* wv      = (const float*)d_in[8];
    const float* wo      = (const float*)d_in[9];
    const float* wff     = (const float*)d_in[10];
    float* out = (float*)d_out;
    char* ws = (char*)d_ws;

    float* f32a = (float*)(ws + 0);             // 8.4 MB conv ping-pong
    u16* qb    = (u16*)(ws + 8388608);
    u16* kb    = (u16*)(ws + 12582912);
    u16* vb    = (u16*)(ws + 16777216);
    u16* attnb = (u16*)(ws + 20971520);
    u16* wb    = (u16*)(ws + 25165824);
    u16* ptwb = wb;
    u16* wqb = wb + 65536;
    u16* wob = wb + 114688;
    u16* wffb = wb + 131072;
    int*   nsumI  = (int*)(ws + 25460736);
    float* scaleQ = (float*)(ws + 25460800);

    k_cvtw<<<576, 256, 0, stream>>>(pt_w, wq, wk, wv, wo, wff, wb);
    k_nsum<<<16, 256, 0, stream>>>(mask, nsumI, scaleQ);

    // conv layers ping-pong: emb -> f32a -> out -> f32a -> out
    const float* src[4] = {emb, f32a, out, f32a};
    float* dst[4] = {f32a, out, f32a, out};
    for (int i = 0; i < 4; i++) {
        k_convlayer<<<512, 256, 0, stream>>>(src[i], ptwb + i * 16384, depth_w + i * 896,
                                             depth_b + i * 128, pt_b + i * 128, dst[i]);
    }
    // LN + QKV (batched over y); Q pre-scaled by rsqrt(nsum)*log2e
    {
        dim3 g3(256, 3);
        k_lngemm<<<g3, 256, 0, stream>>>(out, wqb, 16384, qb, 2097152, scaleQ);
    }
    k_attn<<<1024, 512, 0, stream>>>(qb, kb, vb, nsumI, attnb);
    // wo GEMM + residual + LN + ff GEMM + residual -> out
    k_wolnff<<<256, 256, 0, stream>>>(attnb, wob, wffb, out, out);
}

// Round 11
// 108.293 us; speedup vs baseline: 1.2994x; 1.0768x over previous
//
#include <hip/hip_runtime.h>

typedef unsigned short u16;
typedef float f32x4 __attribute__((ext_vector_type(4)));
typedef unsigned int u32x4 __attribute__((ext_vector_type(4)));
typedef unsigned short u16x4 __attribute__((ext_vector_type(4)));
typedef unsigned short u16x8 __attribute__((ext_vector_type(8)));
typedef __bf16 bf16x8 __attribute__((ext_vector_type(8)));

#define DEVFN static __device__ __forceinline__

DEVFN float bf2f(u16 u) {
    unsigned int i = ((unsigned int)u) << 16;
    float f;
    __builtin_memcpy(&f, &i, 4);
    return f;
}
DEVFN u16 f2bf(float f) {
    unsigned int i;
    __builtin_memcpy(&i, &f, 4);
    unsigned int r = i + 0x7fffu + ((i >> 16) & 1u);
    return (u16)(r >> 16);
}

DEVFN bf16x8 ldb(const u16* p) { return __builtin_bit_cast(bf16x8, *(const u16x8*)p); }

// 16x16x32: C/D: col=lane&15 (Brow), row=(lane>>4)*4+reg (Arow)  (HW-verified r2)
DEVFN f32x4 mfma16(bf16x8 a, bf16x8 b, f32x4 c) {
    return __builtin_amdgcn_mfma_f32_16x16x32_bf16(a, b, c, 0, 0, 0);
}

// raw v_exp_f32 (skips denormal fixup). Args are |x|<~4 or -1e30 (raw op -> 0). [r10: WIN]
#if __has_builtin(__builtin_amdgcn_exp2f)
DEVFN float ex2(float x) { return __builtin_amdgcn_exp2f(x); }
#else
DEVFN float ex2(float x) { return exp2f(x); }
#endif

// ---------------- weight convert: fp32 -> bf16 ----------------
__global__ __launch_bounds__(256) void k_cvtw(const float* __restrict__ pt,
                                              const float* __restrict__ q,
                                              const float* __restrict__ k,
                                              const float* __restrict__ v,
                                              const float* __restrict__ o,
                                              const float* __restrict__ f,
                                              u16* __restrict__ dst) {
    int i = blockIdx.x * 256 + threadIdx.x;  // grid covers exactly 147456
    const float* s;
    int off;
    if (i < 65536)       { s = pt; off = i; }
    else if (i < 81920)  { s = q;  off = i - 65536; }
    else if (i < 98304)  { s = k;  off = i - 81920; }
    else if (i < 114688) { s = v;  off = i - 98304; }
    else if (i < 131072) { s = o;  off = i - 114688; }
    else                 { s = f;  off = i - 131072; }
    dst[i] = f2bf(s[off]);
}

// ---------------- per-batch mask sum + Q scale ----------------
__global__ __launch_bounds__(256) void k_nsum(const int* __restrict__ mask,
                                              int* __restrict__ nsumI,
                                              float* __restrict__ scaleQ) {
    __shared__ int sred[4];
    int tid = threadIdx.x, b = blockIdx.x;
    int4 mm = *(const int4*)&mask[(b << 10) + tid * 4];
    int part = mm.x + mm.y + mm.z + mm.w;
#pragma unroll
    for (int off = 1; off < 64; off <<= 1) part += __shfl_xor(part, off);
    if ((tid & 63) == 0) sred[tid >> 6] = part;
    __syncthreads();
    if (tid == 0) {
        int n = sred[0] + sred[1] + sred[2] + sred[3];
        nsumI[b] = n;
        scaleQ[b] = rsqrtf((float)n) * 1.44269504089f;  // fold log2(e) for exp2 softmax
    }
}

// ---------------- fused 4-layer conv stack: (LN + dwconv + pointwise + residual) x4 ----------------
// grid = 512 (b*32 + lt), block = 512 (8 waves). 32 output rows/block, halo recompute (+-12 in).
// LDS: sCur fp32[56][128] 28.7KB + sLC (lnv/convt) 16KB + sW 32KB = 77KB -> 2 blocks/CU.
__global__ __launch_bounds__(512) void k_convstack(const float* __restrict__ x,
                                                   const u16* __restrict__ Wall,
                                                   const float* __restrict__ dwAll,
                                                   const float* __restrict__ dbAll,
                                                   const float* __restrict__ pbAll,
                                                   float* __restrict__ dst) {
    __shared__ alignas(16) float sCur[56 * 128];  // fp32 residual stream, idx = abs row - (l0-12)
    __shared__ alignas(16) u16 sLC[64 * 128];     // phase A: LN'ed rows; phase B: swizzled conv tile
    __shared__ alignas(16) u16 sW[128 * 128];     // pointwise W (swizzled), restaged per layer
    int tid = threadIdx.x;
    int w = tid >> 6, l64 = tid & 63;
    int b = blockIdx.x >> 5, lt = blockIdx.x & 31;
    int l0 = lt << 5;
    const float* xb = x + ((size_t)(b << 10)) * 128;
    float* dstb = dst + ((size_t)(b << 10)) * 128;
    int row16 = l64 & 15, g = l64 >> 4;
    f32x4 zf = {0.f, 0.f, 0.f, 0.f};

    for (int j = 0; j < 4; j++) {
        int lo = 3 * j;          // valid input rows [lo, hi)
        int hi = 56 - 3 * j;
        int cstart = lo + 3;     // conv output rows [cstart, cstart+width)
        int width = 50 - 6 * j;

        // --- LN phase: wave-per-row (stride 8) ---
        for (int r = lo + w; r < hi; r += 8) {
            int al = l0 - 12 + r;
            bool ok = (al >= 0) && (al < 1024);
            float2 v = {0.f, 0.f};
            if (ok) {
                if (j == 0) v = *(const float2*)&xb[(size_t)al * 128 + (l64 << 1)];
                else        v = *(const float2*)&sCur[r * 128 + (l64 << 1)];
            }
            if (j == 0) *(float2*)&sCur[r * 128 + (l64 << 1)] = v;
            float s = v.x + v.y, q = v.x * v.x + v.y * v.y;
#pragma unroll
            for (int off = 1; off < 64; off <<= 1) {
                s += __shfl_xor(s, off);
                q += __shfl_xor(q, off);
            }
            float mean = s * (1.0f / 128.0f);
            float var = q * (1.0f / 128.0f) - mean * mean;
            float rs = rsqrtf(var + 1e-5f);
            unsigned int pk = 0;
            if (ok)
                pk = (unsigned int)f2bf((v.x - mean) * rs) |
                     ((unsigned int)f2bf((v.y - mean) * rs) << 16);
            *(unsigned int*)&sLC[r * 128 + (l64 << 1)] = pk;
        }
        __syncthreads();

        // --- stage W_j (overlaps conv compute) ---
        const u16* Wp = Wall + j * 16384;
#pragma unroll
        for (int i = 0; i < 4; i++) {
            int e = i * 512 + tid;
            int r = e >> 4, cc = e & 15;
            *(u32x4*)&sW[r * 128 + ((cc ^ (r & 15)) << 3)] =
                *(const u32x4*)&Wp[(r << 7) + (cc << 3)];
        }

        // --- depthwise conv to regs: wave w owns 7 rows, lane = channel pair ---
        int cp = l64;
        const float* dwp = dwAll + j * 896;
        float w0[7], w1[7];
#pragma unroll
        for (int k = 0; k < 7; k++) {
            w0[k] = dwp[(cp * 2) * 7 + k];
            w1[k] = dwp[(cp * 2 + 1) * 7 + k];
        }
        float b0 = dbAll[j * 128 + cp * 2], b1 = dbAll[j * 128 + cp * 2 + 1];
        int base = cstart + w * 7;
        float v0[13], v1[13];
#pragma unroll
        for (int k = 0; k < 13; k++) {
            int rw = base - 3 + k;
            rw = rw < 63 ? rw : 63;  // clamp (garbage only feeds discarded rows)
            unsigned int pk = *(const unsigned int*)&sLC[rw * 128 + (cp << 1)];
            v0[k] = bf2f((u16)(pk & 0xffffu));
            v1[k] = bf2f((u16)(pk >> 16));
        }
        float a0[7], a1[7];
#pragma unroll
        for (int rr = 0; rr < 7; rr++) {
            float s0 = b0, s1 = b1;
#pragma unroll
            for (int k = 0; k < 7; k++) {
                s0 += v0[rr + k] * w0[k];
                s1 += v1[rr + k] * w1[k];
            }
            a0[rr] = s0;
            a1[rr] = s1;
        }
        __syncthreads();

        // --- write conv tile (relative rows, swizzled) + zero pad rows ---
#pragma unroll
        for (int rr = 0; rr < 7; rr++) {
            int rel = w * 7 + rr;  // 0..55
            float s0 = (rel < width) ? a0[rr] : 0.0f;
            float s1 = (rel < width) ? a1[rr] : 0.0f;
            int cc = cp >> 2;
            *(unsigned int*)&sLC[rel * 128 + ((cc ^ (rel & 15)) << 3) + ((cp & 3) << 1)] =
                (unsigned int)f2bf(s0) | ((unsigned int)f2bf(s1) << 16);
        }
        *(unsigned int*)&sLC[(56 + w) * 128 + (l64 << 1)] = 0;  // rows 56..63
        __syncthreads();

        // --- pointwise GEMM 64x128x128 (padded): wave = (mh = w>>1, nh = w&1) ---
        int mh = w >> 1, nh = w & 1;
        f32x4 acc[4] = {zf, zf, zf, zf};
#pragma unroll
        for (int kk = 0; kk < 4; kk++) {
            int chunk = ((kk * 4 + g) ^ row16) << 3;
            bf16x8 a = ldb(&sLC[(mh * 16 + row16) * 128 + chunk]);
#pragma unroll
            for (int n = 0; n < 4; n++) {
                bf16x8 bfr = ldb(&sW[(nh * 64 + n * 16 + row16) * 128 + chunk]);
                acc[n] = mfma16(a, bfr, acc[n]);
            }
        }
        const float* pbp = pbAll + j * 128;
#pragma unroll
        for (int n = 0; n < 4; n++) {
            int col = nh * 64 + n * 16 + row16;
            float bi = pbp[col];
#pragma unroll
            for (int r = 0; r < 4; r++) {
                int rel = mh * 16 + g * 4 + r;
                if (rel < width) {
                    int idx = cstart + rel;
                    float val = acc[n][r] + bi + sCur[idx * 128 + col];
                    sCur[idx * 128 + col] = val;
                    if (j == 3) dstb[(size_t)(l0 + rel) * 128 + col] = val;
                }
            }
        }
        __syncthreads();
    }
}

// ---------------- fused LN + GEMM: Y = LN(X) @ W^T -> bf16 (QKV; Q pre-scaled) ----------------
__global__ __launch_bounds__(256) void k_lngemm(const float* __restrict__ x,
                                                const u16* __restrict__ Wb, int wstride,
                                                u16* __restrict__ dstb, int dstride,
                                                const float* __restrict__ scaleQ) {
    __shared__ alignas(16) u16 sX[64 * 128];
    __shared__ alignas(16) u16 sW[128 * 128];
    const u16* Wp = Wb + (size_t)blockIdx.y * wstride;
    dstb += (size_t)blockIdx.y * dstride;
    float qs = (blockIdx.y == 0) ? scaleQ[blockIdx.x >> 4] : 1.0f;
    int tid = threadIdx.x;
    int w = tid >> 6, l64 = tid & 63;
    int rbase = blockIdx.x * 64;

#pragma unroll
    for (int j = 0; j < 8; j++) {
        int e = j * 256 + tid;
        int r = e >> 4, cc = e & 15;
        *(u32x4*)&sW[r * 128 + ((cc ^ (r & 15)) << 3)] = *(const u32x4*)&Wp[(r << 7) + (cc << 3)];
    }
    for (int r = w; r < 64; r += 4) {
        float2 v = *(const float2*)&x[((size_t)(rbase + r)) * 128 + (l64 << 1)];
        float s = v.x + v.y, q = v.x * v.x + v.y * v.y;
#pragma unroll
        for (int off = 1; off < 64; off <<= 1) {
            s += __shfl_xor(s, off);
            q += __shfl_xor(q, off);
        }
        float mean = s * (1.0f / 128.0f);
        float var = q * (1.0f / 128.0f) - mean * mean;
        float rs = rsqrtf(var + 1e-5f);
        unsigned int pk = (unsigned int)f2bf((v.x - mean) * rs) |
                          ((unsigned int)f2bf((v.y - mean) * rs) << 16);
        int cc = l64 >> 2;
        *(unsigned int*)&sX[r * 128 + ((cc ^ (r & 15)) << 3) + ((l64 & 3) << 1)] = pk;
    }
    __syncthreads();

    int row16 = l64 & 15, g = l64 >> 4;
    f32x4 zf = {0.f, 0.f, 0.f, 0.f};
    f32x4 acc[8];
#pragma unroll
    for (int n = 0; n < 8; n++) acc[n] = zf;
#pragma unroll
    for (int kk = 0; kk < 4; kk++) {
        int chunk = ((kk * 4 + g) ^ row16) << 3;
        bf16x8 a = ldb(&sX[(w * 16 + row16) * 128 + chunk]);
#pragma unroll
        for (int n = 0; n < 8; n++) {
            bf16x8 bfr = ldb(&sW[(n * 16 + row16) * 128 + chunk]);
            acc[n] = mfma16(a, bfr, acc[n]);
        }
    }
    int r0 = rbase + w * 16 + g * 4;
#pragma unroll
    for (int n = 0; n < 8; n++) {
        int col = n * 16 + row16;
#pragma unroll
        for (int r = 0; r < 4; r++)
            dstb[(size_t)(r0 + r) * 128 + col] = f2bf(acc[n][r] * qs);
    }
}

// ---------------- fused wo-GEMM + residual + LN + ff-GEMM + residual ----------------
__global__ __launch_bounds__(256) void k_wolnff(const u16* __restrict__ X,
                                                const u16* __restrict__ Wo,
                                                const u16* __restrict__ Wff,
                                                const float* __restrict__ res,
                                                float* __restrict__ dst) {
    __shared__ alignas(16) u16 sX[64 * 128];
    __shared__ alignas(16) u16 sW1[128 * 128];
    __shared__ alignas(16) u16 sW2[128 * 128];
    int tid = threadIdx.x;
    int w = tid >> 6, l64 = tid & 63;
    int rbase = blockIdx.x * 64;
#pragma unroll
    for (int j = 0; j < 8; j++) {
        int e = j * 256 + tid;
        int r = e >> 4, cc = e & 15;
        int sw = ((cc ^ (r & 15)) << 3);
        *(u32x4*)&sW1[r * 128 + sw] = *(const u32x4*)&Wo[(r << 7) + (cc << 3)];
        *(u32x4*)&sW2[r * 128 + sw] = *(const u32x4*)&Wff[(r << 7) + (cc << 3)];
    }
#pragma unroll
    for (int j = 0; j < 4; j++) {
        int e = j * 256 + tid;
        int r = e >> 4, cc = e & 15;
        *(u32x4*)&sX[r * 128 + ((cc ^ (r & 15)) << 3)] =
            *(const u32x4*)&X[((rbase + r) << 7) + (cc << 3)];
    }
    __syncthreads();

    int row16 = l64 & 15, g = l64 >> 4;
    f32x4 zf = {0.f, 0.f, 0.f, 0.f};
    f32x4 acc[8];
#pragma unroll
    for (int n = 0; n < 8; n++) acc[n] = zf;
#pragma unroll
    for (int kk = 0; kk < 4; kk++) {
        int chunk = ((kk * 4 + g) ^ row16) << 3;
        bf16x8 a = ldb(&sX[(w * 16 + row16) * 128 + chunk]);
#pragma unroll
        for (int n = 0; n < 8; n++) {
            bf16x8 bfr = ldb(&sW1[(n * 16 + row16) * 128 + chunk]);
            acc[n] = mfma16(a, bfr, acc[n]);
        }
    }
    f32x4 vals[8];
#pragma unroll
    for (int n = 0; n < 8; n++) {
        int col = n * 16 + row16;
#pragma unroll
        for (int r = 0; r < 4; r++)
            vals[n][r] = acc[n][r] + res[(size_t)(rbase + w * 16 + g * 4 + r) * 128 + col];
    }
    float mean[4], rstd[4];
#pragma unroll
    for (int r = 0; r < 4; r++) {
        float s = 0.f, q = 0.f;
#pragma unroll
        for (int n = 0; n < 8; n++) {
            s += vals[n][r];
            q += vals[n][r] * vals[n][r];
        }
#pragma unroll
        for (int off = 1; off < 16; off <<= 1) {
            s += __shfl_xor(s, off);
            q += __shfl_xor(q, off);
        }
        mean[r] = s * (1.0f / 128.0f);
        float var = q * (1.0f / 128.0f) - mean[r] * mean[r];
        rstd[r] = rsqrtf(var + 1e-5f);
    }
    __syncthreads();
#pragma unroll
    for (int n = 0; n < 8; n++) {
        int col = n * 16 + row16;
        int cc = col >> 3;
#pragma unroll
        for (int r = 0; r < 4; r++) {
            int row = w * 16 + g * 4 + r;
            sX[row * 128 + ((cc ^ (row & 15)) << 3) + (row16 & 7)] =
                f2bf((vals[n][r] - mean[r]) * rstd[r]);
        }
    }
    __syncthreads();
    f32x4 acc2[8];
#pragma unroll
    for (int n = 0; n < 8; n++) acc2[n] = zf;
#pragma unroll
    for (int kk = 0; kk < 4; kk++) {
        int chunk = ((kk * 4 + g) ^ row16) << 3;
        bf16x8 a = ldb(&sX[(w * 16 + row16) * 128 + chunk]);
#pragma unroll
        for (int n = 0; n < 8; n++) {
            bf16x8 bfr = ldb(&sW2[(n * 16 + row16) * 128 + chunk]);
            acc2[n] = mfma16(a, bfr, acc2[n]);
        }
    }
#pragma unroll
    for (int n = 0; n < 8; n++) {
        int col = n * 16 + row16;
#pragma unroll
        for (int r = 0; r < 4; r++)
            dst[(size_t)(rbase + w * 16 + g * 4 + r) * 128 + col] = vals[n][r] + acc2[n][r];
    }
}

// ---------------- fused attention (r10: r5 structure + prescaled Q + raw v_exp) ----------------
#define LOAD_VF(P)                                                                             \
    bf16x8 vf;                                                                                 \
    {                                                                                          \
        const u16* vp = &sVt[row16 * 1032 + (P) * 32 + (g << 2)];                              \
        union { u16x4 h[2]; u16x8 v8; } uu;                                                    \
        uu.h[0] = *(const u16x4*)vp;                                                           \
        uu.h[1] = *(const u16x4*)(vp + 16);                                                    \
        vf = __builtin_bit_cast(bf16x8, uu.v8);                                                \
    }

#define SM_PV(SV)                                                                              \
    {                                                                                          \
        float p0 = ex2(SV[0]), p1 = ex2(SV[1]), p2 = ex2(SV[2]), p3 = ex2(SV[3]);              \
        float p4 = ex2(SV[4]), p5 = ex2(SV[5]), p6 = ex2(SV[6]), p7 = ex2(SV[7]);              \
        lrun += ((p0 + p1) + (p2 + p3)) + ((p4 + p5) + (p6 + p7));                             \
        bf16x8 pa = {(__bf16)p0, (__bf16)p1, (__bf16)p2, (__bf16)p3,                           \
                     (__bf16)p4, (__bf16)p5, (__bf16)p6, (__bf16)p7};                          \
        oacc = mfma16(vf, pa, oacc);                                                           \
    }

__global__ __launch_bounds__(512) void k_attn(const u16* __restrict__ Qg, const u16* __restrict__ Kg,
                                              const u16* __restrict__ Vg,
                                              const int* __restrict__ nsumI,
                                              u16* __restrict__ Og) {
    __shared__ alignas(16) u16 sVt[16 * 1032];  // 33KB: [d][m], row-padded +8
    int tid = threadIdx.x;
    int w = tid >> 6, l = tid & 63;
    int bh = blockIdx.x >> 3;
    int qblk = blockIdx.x & 7;
    int b = bh >> 3, h = bh & 7;
    int row16 = l & 15, g = l >> 4;

    const u16* kg = Kg + (size_t)(b << 10) * 128 + (h << 4);
    const u16* vg = Vg + (size_t)(b << 10) * 128 + (h << 4);
#pragma unroll
    for (int j = 0; j < 4; j++) {
        int e = j * 512 + tid;
        int m = e >> 1, half = e & 1;
        u32x4 vv = *(const u32x4*)&vg[m * 128 + half * 8];
        union { u32x4 q; u16 s[8]; } u;
        u.q = vv;
#pragma unroll
        for (int jj = 0; jj < 8; jj++) sVt[(half * 8 + jj) * 1032 + m] = u.s[jj];
    }
    __syncthreads();
    int nsum = nsumI[b];

    int qbase = qblk * 128 + w * 16;
    u16x8 z8 = {0, 0, 0, 0, 0, 0, 0, 0};
    const bf16x8 zb = __builtin_bit_cast(bf16x8, z8);
    f32x4 zf = {0.f, 0.f, 0.f, 0.f};

    bool rowv = (qbase + row16) < nsum;
    bf16x8 qf = zb;
    if (rowv && g < 2)  // pre-scaled Q (rsqrt(nsum)*log2e folded); invalid rows: S=0 -> P=1
        qf = ldb(&Qg[(size_t)((b << 10) + qbase + row16) * 128 + (h << 4) + (g << 3)]);
    f32x4 oacc = zf;
    float lrun = 0.0f;

    const u16* kl = kg + row16 * 128 + (g << 3);  // per-lane K ptr (g<2 lanes), +8KB/pair
    int p = 0;
    if (qbase < nsum) {  // wave has at least one valid q-row
        int full = nsum >> 5;
        for (; p < full; p++) {
            bf16x8 kf0 = zb, kf1 = zb;
            if (g < 2) {
                kf0 = ldb(kl);
                kf1 = ldb(kl + 2048);
            }
            LOAD_VF(p)
            kl += 4096;
            f32x4 s0 = mfma16(kf0, qf, zf);
            f32x4 s1 = mfma16(kf1, qf, zf);
            float sv[8];
#pragma unroll
            for (int r = 0; r < 4; r++) {
                sv[r] = s0[r];
                sv[4 + r] = s1[r];
            }
            SM_PV(sv)
        }
        if (nsum & 31) {  // one partial pair
            bf16x8 kf0 = zb, kf1 = zb;
            if (g < 2) {
                kf0 = ldb(kl);
                kf1 = ldb(kl + 2048);
            }
            LOAD_VF(p)
            int kb_ = p << 5;
            f32x4 s0 = mfma16(kf0, qf, zf);
            f32x4 s1 = mfma16(kf1, qf, zf);
            float negfill = rowv ? -1.0e30f : 0.0f;  // invalid rows: P=1 on all cols
            float sv[8];
#pragma unroll
            for (int r = 0; r < 4; r++) {
                sv[r] = ((kb_ + (g << 2) + r) < nsum) ? s0[r] : negfill;
                sv[4 + r] = ((kb_ + 16 + (g << 2) + r) < nsum) ? s1[r] : negfill;
            }
            SM_PV(sv)
            p++;
        }
    }
    if (qbase + 16 > nsum && p < 32) {  // waves holding invalid rows: constant P tail
        int ntail = 32 - p;
        __bf16 vcst = rowv ? (__bf16)0.0f : (__bf16)1.0f;
        bf16x8 pt = {vcst, vcst, vcst, vcst, vcst, vcst, vcst, vcst};
        if (!rowv) lrun += 8.0f * (float)ntail;
        for (; p < 32; p++) {
            LOAD_VF(p)
            oacc = mfma16(vf, pt, oacc);
        }
    }

    float lr = lrun;
    lr += __shfl_xor(lr, 16);
    lr += __shfl_xor(lr, 32);
    float inv = 1.0f / lr;
    u16x4 ov;
#pragma unroll
    for (int r = 0; r < 4; r++) ov[r] = f2bf(oacc[r] * inv);
    int q = qbase + row16;
    *(u16x4*)&Og[(size_t)((b << 10) + q) * 128 + (h << 4) + (g << 2)] = ov;
}

extern "C" void kernel_launch(void* const* d_in, const int* in_sizes, int n_in,
                              void* d_out, int out_size, void* d_ws, size_t ws_size,
                              hipStream_t stream) {
    const float* emb     = (const float*)d_in[0];
    const int*   mask    = (const int*)d_in[1];
    const float* depth_w = (const float*)d_in[2];
    const float* depth_b = (const float*)d_in[3];
    const float* pt_w    = (const float*)d_in[4];
    const float* pt_b    = (const float*)d_in[5];
    const float* wq      = (const float*)d_in[6];
    const float* wk      = (const float*)d_in[7];
    const float* wv      = (const float*)d_in[8];
    const float* wo      = (const float*)d_in[9];
    const float* wff     = (const float*)d_in[10];
    float* out = (float*)d_out;
    char* ws = (char*)d_ws;

    float* f32a = (float*)(ws + 0);
    u16* qb    = (u16*)(ws + 8388608);
    u16* kb    = (u16*)(ws + 12582912);
    u16* vb    = (u16*)(ws + 16777216);
    u16* attnb = (u16*)(ws + 20971520);
    u16* wb    = (u16*)(ws + 25165824);
    u16* ptwb = wb;
    u16* wqb = wb + 65536;
    u16* wob = wb + 114688;
    u16* wffb = wb + 131072;
    int*   nsumI  = (int*)(ws + 25460736);
    float* scaleQ = (float*)(ws + 25460800);
    (void)f32a;

    k_cvtw<<<576, 256, 0, stream>>>(pt_w, wq, wk, wv, wo, wff, wb);
    k_nsum<<<16, 256, 0, stream>>>(mask, nsumI, scaleQ);

    // all 4 conv layers in one kernel: emb -> out
    k_convstack<<<512, 512, 0, stream>>>(emb, ptwb, depth_w, depth_b, pt_b, out);

    // LN + QKV (batched over y); Q pre-scaled by rsqrt(nsum)*log2e
    {
        dim3 g3(256, 3);
        k_lngemm<<<g3, 256, 0, stream>>>(out, wqb, 16384, qb, 2097152, scaleQ);
    }
    k_attn<<<1024, 512, 0, stream>>>(qb, kb, vb, nsumI, attnb);
    // wo GEMM + residual + LN + ff GEMM + residual -> out
    k_wolnff<<<256, 256, 0, stream>>>(attnb, wob, wffb, out, out);
}